// Round 17
// baseline (127.505 us; speedup 1.0000x reference)
//
#include <hip/hip_runtime.h>
#include <math.h>

// HoltWintersDecomposition: x (8192, 2048) f32, sequential per-row recurrence.
// r17 = r15 chain + ILP-2 producer + consumer-side y + 4 consumer waves.
//   Model (r13-r16 calibrated): step = issue (~32cy) + exposed rcp latency
//   (~50cy) ~ 82cy, both convert 1:1. ILP-2: each producer lane runs TWO rows
//   (i, i+32); sibling chain's issue fills the rcp stalls -> ~58cy per TWO
//   row-steps. r12's ILP-2 confounders removed: 32 active lanes (not 16), x in
//   registers (not LDS), lean 2-rcp step, no y on producer.
//   y offloaded to consumers: y = x*rcp(lte*ste) (validated primed form;
//   consumers re-load x from L3), removing y's rcp+muls and all YT LDS.
//   128 blocks x 64 rows; block = producer + 4 consumer waves (12KB/tile each
//   -> drains overlap; device write floor ~196MB/4.5TBps ~ 44us).
//   Producer x: half-tile double-buffer per row; the post-barrier refill obeys
//   r9's vmcnt-drain lesson (1650cy lead, L3-resident).
// Lessons: r6 parallel-in-time mathematically broken (s ~ 20*EPS); r9 producer
// loads need lead >= load latency past any barrier; r16 both rcps are serial.

constexpr int   T    = 2048;
constexpr int   B    = 8192;
constexpr int   RPB  = 64;        // rows per block
constexpr int   TT   = 64;        // steps per tile
constexpr int   NTI  = T / TT;    // 32 tiles
constexpr int   LSX  = 68;        // LDS stride words: 272B rows, 16B-aligned
constexpr float EPS  = 1e-8f;

__global__ __launch_bounds__(320, 1)
void hw_kernel(const float* __restrict__ x,
               const float* __restrict__ pla,
               const float* __restrict__ plg,
               float* __restrict__ out)
{
    __shared__ alignas(16) float LT[2][RPB][LSX];
    __shared__ alignas(16) float ST[2][RPB][LSX];

    const int tid  = threadIdx.x;
    const int wid  = tid >> 6;        // 0 = producer, 1..4 = consumers
    const int lane = tid & 63;
    const int row0 = blockIdx.x * RPB;

    const float alpha = 1.0f / (1.0f + expf(-pla[0]));
    const float gamma = 1.0f / (1.0f + expf(-plg[0]));
    const float oma = 1.0f - alpha, omg = 1.0f - gamma;
    const float EPSa = EPS * alpha;   // folds +EPS into the l fma constant
    const float EPSg = EPS * gamma;   // folds +EPS into the s fma constant

    float* __restrict__ lout = out;
    float* __restrict__ sout = out + (size_t)B * T;
    float* __restrict__ yout = out + (size_t)2 * B * T;

    if (wid == 0) {
        // ========== producer: 32 active lanes x 2 rows (i, i+32) ==========
        const bool act = lane < 32;
        const int  li  = lane & 31;
        const float* __restrict__ xrowA = x + (size_t)(row0 + li) * T;
        const float* __restrict__ xrowB = x + (size_t)(row0 + 32 + li) * T;

        float lpeA = 0.f, speA = 1.f;   // primed state row A: l+EPS, s+EPS
        float lpeB = 0.f, speB = 1.f;   // primed state row B

        float4 CA[8], CB[8], NA[8], NB[8];   // half-tile x bufs (cur, next)

        auto loadHalf = [&](float4* RA, float4* RB, int k, int h) {
            const float* pA = xrowA + k * TT + h * 32;
            const float* pB = xrowB + k * TT + h * 32;
            #pragma unroll
            for (int i = 0; i < 8; ++i) {
                RA[i] = *reinterpret_cast<const float4*>(pA + 4 * i);
                RB[i] = *reinterpret_cast<const float4*>(pB + 4 * i);
            }
        };

        // two interleaved lean steps (2 rcp + 6 VALU each)
        auto step2 = [&](float xA, float xB,
                         float& lA, float& sA, float& lB, float& sB) {
            const float rsA = __builtin_amdgcn_rcpf(speA);
            const float rsB = __builtin_amdgcn_rcpf(speB);
            const float clA = __builtin_fmaf(oma, lpeA, EPSa);
            const float clB = __builtin_fmaf(oma, lpeB, EPSa);
            const float lteA = __builtin_fmaf(alpha * xA, rsA, clA);
            const float lteB = __builtin_fmaf(alpha * xB, rsB, clB);
            const float csA = __builtin_fmaf(omg, speA, EPSg);
            const float csB = __builtin_fmaf(omg, speB, EPSg);
            const float rlA = __builtin_amdgcn_rcpf(lteA);
            const float rlB = __builtin_amdgcn_rcpf(lteB);
            const float steA = __builtin_fmaf(gamma * xA, rlA, csA);
            const float steB = __builtin_fmaf(gamma * xB, rlB, csB);
            lA = lteA; sA = steA; lB = lteB; sB = steB;
            lpeA = lteA; speA = steA; lpeB = lteB; speB = steB;
        };

        auto computeHalf = [&](const float4* RA, const float4* RB,
                               int k, int h, bool first) {
            const int bsel = k & 1;
            const int base = h * 32;
            #pragma unroll
            for (int g = 0; g < 8; ++g) {
                const float4 xa = RA[g];
                const float4 xb = RB[g];
                float4 lvA, svA, lvB, svB;
                if (first && g == 0) {
                    // t == 0: l0 = x0, s0 = 1 (primed store)
                    lpeA = xa.x + EPS; speA = 1.0f + EPS;
                    lvA.x = lpeA; svA.x = speA;
                    lpeB = xb.x + EPS; speB = 1.0f + EPS;
                    lvB.x = lpeB; svB.x = speB;
                    step2(xa.y, xb.y, lvA.y, svA.y, lvB.y, svB.y);
                    step2(xa.z, xb.z, lvA.z, svA.z, lvB.z, svB.z);
                    step2(xa.w, xb.w, lvA.w, svA.w, lvB.w, svB.w);
                } else {
                    step2(xa.x, xb.x, lvA.x, svA.x, lvB.x, svB.x);
                    step2(xa.y, xb.y, lvA.y, svA.y, lvB.y, svB.y);
                    step2(xa.z, xb.z, lvA.z, svA.z, lvB.z, svB.z);
                    step2(xa.w, xb.w, lvA.w, svA.w, lvB.w, svB.w);
                }
                const int c = base + 4 * g;
                *reinterpret_cast<float4*>(&LT[bsel][li][c])      = lvA;
                *reinterpret_cast<float4*>(&ST[bsel][li][c])      = svA;
                *reinterpret_cast<float4*>(&LT[bsel][32 + li][c]) = lvB;
                *reinterpret_cast<float4*>(&ST[bsel][32 + li][c]) = svB;
            }
        };

        if (act) { loadHalf(CA, CB, 0, 0); loadHalf(NA, NB, 0, 1); }

        #pragma unroll 1
        for (int k = 0; k < NTI; ++k) {
            if (act) {
                computeHalf(CA, CB, k, 0, k == 0);
                if (k + 1 < NTI) loadHalf(CA, CB, k + 1, 0);  // 0.5-tile lead
                computeHalf(NA, NB, k, 1, false);
            }
            __syncthreads();
            if (act && k + 1 < NTI) loadHalf(NA, NB, k + 1, 1); // post-barrier
        }
    } else {
        // ========== consumers: stores + y compute, 4 it-groups each ========
        const int cr = lane >> 4;          // 0..3
        const int cc = (lane & 15) << 2;   // 0,4,...,60
        const int itlo = (wid - 1) * 4;

        auto store_tile = [&](int m) {
            const int bsel = m & 1;
            const int t0 = m * TT;
            for (int it = itlo; it < itlo + 4; ++it) {
                const int r = 4 * it + cr;
                const size_t g = (size_t)(row0 + r) * T + t0 + cc;
                const float4 vl = *reinterpret_cast<const float4*>(&LT[bsel][r][cc]);
                const float4 vs = *reinterpret_cast<const float4*>(&ST[bsel][r][cc]);
                const float4 xv = *reinterpret_cast<const float4*>(&x[g]);
                float4 vy;
                vy.x = xv.x * __builtin_amdgcn_rcpf(vl.x * vs.x);
                vy.y = xv.y * __builtin_amdgcn_rcpf(vl.y * vs.y);
                vy.z = xv.z * __builtin_amdgcn_rcpf(vl.z * vs.z);
                vy.w = xv.w * __builtin_amdgcn_rcpf(vl.w * vs.w);
                *reinterpret_cast<float4*>(&lout[g]) = vl;
                *reinterpret_cast<float4*>(&sout[g]) = vs;
                *reinterpret_cast<float4*>(&yout[g]) = vy;
            }
        };

        #pragma unroll 1
        for (int k = 0; k < NTI; ++k) {
            if (k > 0) store_tile(k - 1);
            __syncthreads();
        }
        store_tile(NTI - 1);   // epilogue: tile 31 (buffer 1)
    }
}

extern "C" void kernel_launch(void* const* d_in, const int* in_sizes, int n_in,
                              void* d_out, int out_size, void* d_ws, size_t ws_size,
                              hipStream_t stream) {
    const float* x   = (const float*)d_in[0];
    const float* pla = (const float*)d_in[1];
    const float* plg = (const float*)d_in[2];
    float* out = (float*)d_out;

    dim3 grid(B / RPB);    // 128 blocks x 64 rows
    dim3 block(320);       // wave0 producer (32 lanes x 2 rows), waves 1-4 consumers
    hw_kernel<<<grid, block, 0, stream>>>(x, pla, plg, out);
}

// Round 18
// 68.648 us; speedup vs baseline: 1.8574x; 1.8574x over previous
//
#include <hip/hip_runtime.h>
#include <math.h>

// HoltWintersDecomposition: x (8192, 2048) f32, sequential per-row recurrence.
// r18 = r15 (best, 70.3us) minus producer issue-work:
//   Calibrated model (r13..r17): producer step-time = issue + exposed rcp
//   latency, converting ~1:1 cy-for-cy. ILP-in-wave refuted 3x (r4/r12/r17).
//   So: remove instructions from the producer step.
//   - y moved to consumers (r17-validated numerics: y = x*rcp(l*s) with primed
//     l,s; absmax stayed 16384): producer loses y-mul + xrl-mul + 1/3 of its
//     ds_writes; YT buffer deleted (LDS 52->35KB).
//   - producer step: rcp,fma,rcp,fma chain + cl/cs/axt/gxt off-chain
//     = 2 rcp + 6 VALU + 0.5 ds_write ~ 22 issue-cy (r15: ~28).
//   - TWO consumer waves (r14-proven neutral-safe) carrying stores + y:
//     each half-tile: 3 ds_read_b128 groups, x reload (L3), 4 rcp + 4 mul,
//     3 full-line float4 stores.
// Structure: 256 blocks x 32 rows; wave0 producer (lanes 0..31, full-tile x
// register prefetch, 1-tile lead covers the barrier vmcnt drain); waves 1-2
// consumers; 1 barrier/tile.
// Lessons: r6 parallel-in-time broken (s ~ 20*EPS); r9 producer loads need
// >= 1-tile lead; r4/r12/r17 never pack 2 chains into one wave.

constexpr int   T    = 2048;
constexpr int   B    = 8192;
constexpr int   RPB  = 32;        // rows per block
constexpr int   TT   = 64;        // steps per tile
constexpr int   NTI  = T / TT;    // 32 tiles
constexpr int   LSX  = 68;        // LDS stride words: 272B rows, 16B-aligned
constexpr float EPS  = 1e-8f;

__global__ __launch_bounds__(192, 1)
void hw_kernel(const float* __restrict__ x,
               const float* __restrict__ pla,
               const float* __restrict__ plg,
               float* __restrict__ out)
{
    __shared__ alignas(16) float LT[2][RPB][LSX];
    __shared__ alignas(16) float ST[2][RPB][LSX];

    const int tid  = threadIdx.x;
    const int wid  = tid >> 6;        // 0 = producer, 1..2 = consumers
    const int lane = tid & 63;
    const int row0 = blockIdx.x * RPB;

    const float alpha = 1.0f / (1.0f + expf(-pla[0]));
    const float gamma = 1.0f / (1.0f + expf(-plg[0]));
    const float oma = 1.0f - alpha, omg = 1.0f - gamma;
    const float EPSa = EPS * alpha;   // folds +EPS into the l fma constant
    const float EPSg = EPS * gamma;   // folds +EPS into the s fma constant

    float* __restrict__ lout = out;
    float* __restrict__ sout = out + (size_t)B * T;
    float* __restrict__ yout = out + (size_t)2 * B * T;

    // store-phase lane mapping
    const int cr = lane >> 4;          // 0..3
    const int cc = (lane & 15) << 2;   // 0,4,...,60

    // consumer: stores l/s from LDS + computes y = x*rcp(l*s) (primed form)
    auto store_tile = [&](int m, int itlo, int ithi) {
        const int bsel = m & 1;
        const int t0 = m * TT;
        for (int it = itlo; it < ithi; ++it) {
            const int r = 4 * it + cr;
            const size_t g = (size_t)(row0 + r) * T + t0 + cc;
            const float4 vl = *reinterpret_cast<const float4*>(&LT[bsel][r][cc]);
            const float4 vs = *reinterpret_cast<const float4*>(&ST[bsel][r][cc]);
            const float4 xv = *reinterpret_cast<const float4*>(&x[g]);
            float4 vy;
            vy.x = xv.x * __builtin_amdgcn_rcpf(vl.x * vs.x);
            vy.y = xv.y * __builtin_amdgcn_rcpf(vl.y * vs.y);
            vy.z = xv.z * __builtin_amdgcn_rcpf(vl.z * vs.z);
            vy.w = xv.w * __builtin_amdgcn_rcpf(vl.w * vs.w);
            *reinterpret_cast<float4*>(&lout[g]) = vl;
            *reinterpret_cast<float4*>(&sout[g]) = vs;
            *reinterpret_cast<float4*>(&yout[g]) = vy;
        }
    };

    if (wid == 0) {
        // ================= producer =================
        const bool act = lane < RPB;
        const float* __restrict__ xrow = x + (size_t)(row0 + (act ? lane : 0)) * T;

        float lpe = 0.0f, spe = 1.0f;   // primed state: l+EPS, s+EPS
        float4 XA[16], XB[16];

        auto loadX = [&](float4* Xb, int k) {
            const float* p = xrow + k * TT;
            #pragma unroll
            for (int i = 0; i < 16; ++i)
                Xb[i] = *reinterpret_cast<const float4*>(p + 4 * i);
        };

        // chain: rcp -> fma -> rcp -> fma; constants off-chain; NO y work
        auto do_step = [&](float xt, float& lo, float& so) {
            const float rs  = __builtin_amdgcn_rcpf(spe);         // chain
            const float cl  = __builtin_fmaf(oma, lpe, EPSa);     // off-chain
            const float lte = __builtin_fmaf(alpha * xt, rs, cl); // chain
            const float cs  = __builtin_fmaf(omg, spe, EPSg);     // off-chain
            const float rl  = __builtin_amdgcn_rcpf(lte);         // chain
            const float ste = __builtin_fmaf(gamma * xt, rl, cs); // chain
            lo = lte; so = ste;                                   // primed store
            lpe = lte; spe = ste;
        };

        auto compute_tile = [&](const float4* Xb, int k, bool first) {
            const int bsel = k & 1;
            #pragma unroll
            for (int g = 0; g < 16; ++g) {
                const float4 xv = Xb[g];
                float4 lv, sv;
                if (first && g == 0) {
                    // t == 0: l0 = x0, s0 = 1 (primed)
                    lpe = xv.x + EPS; spe = 1.0f + EPS;
                    lv.x = lpe; sv.x = spe;
                    do_step(xv.y, lv.y, sv.y);
                    do_step(xv.z, lv.z, sv.z);
                    do_step(xv.w, lv.w, sv.w);
                } else {
                    do_step(xv.x, lv.x, sv.x);
                    do_step(xv.y, lv.y, sv.y);
                    do_step(xv.z, lv.z, sv.z);
                    do_step(xv.w, lv.w, sv.w);
                }
                *reinterpret_cast<float4*>(&LT[bsel][lane][4 * g]) = lv;
                *reinterpret_cast<float4*>(&ST[bsel][lane][4 * g]) = sv;
            }
        };

        if (act) { loadX(XA, 0); loadX(XB, 1); }
        if (act) compute_tile(XA, 0, true);     // one-time vmcnt wait on XA
        __syncthreads();

        #pragma unroll 1
        for (int k = 1; k < NTI - 1; k += 2) {
            if (act) { loadX(XA, k + 1); compute_tile(XB, k, false); }
            __syncthreads();
            if (act) { loadX(XB, k + 2); compute_tile(XA, k + 1, false); }
            __syncthreads();
        }
        if (act) compute_tile(XB, NTI - 1, false);
        __syncthreads();
    } else {
        // ================= consumers: stores + y, half tile each =========
        const int lo = (wid - 1) * 4;            // wave1: 0..3, wave2: 4..7
        #pragma unroll 1
        for (int k = 0; k < NTI; ++k) {
            if (k > 0) store_tile(k - 1, lo, lo + 4);
            __syncthreads();
        }
    }

    // epilogue: tile 31 (buffer 1), all three waves split the 8 store groups
    {
        const int lo = (wid == 0) ? 0 : (wid == 1) ? 2 : 5;
        const int hi = (wid == 0) ? 2 : (wid == 1) ? 5 : 8;
        store_tile(NTI - 1, lo, hi);
    }
}

extern "C" void kernel_launch(void* const* d_in, const int* in_sizes, int n_in,
                              void* d_out, int out_size, void* d_ws, size_t ws_size,
                              hipStream_t stream) {
    const float* x   = (const float*)d_in[0];
    const float* pla = (const float*)d_in[1];
    const float* plg = (const float*)d_in[2];
    float* out = (float*)d_out;

    dim3 grid(B / RPB);    // 256 blocks -> one producer + 2 consumers per CU
    dim3 block(192);       // wave0 producer (32 rows), waves 1-2 consumers
    hw_kernel<<<grid, block, 0, stream>>>(x, pla, plg, out);
}

// Round 19
// 61.917 us; speedup vs baseline: 2.0593x; 1.1087x over previous
//
#include <hip/hip_runtime.h>
#include <math.h>

// HoltWintersDecomposition: x (8192, 2048) f32, sequential per-row recurrence.
// r19 = r18 + ONE-rcp product-state recurrence:
//   Carry D = lte*ste alongside lte. Exact algebra (ste*rcp(ste)=1+O(2.5e-7),
//   drop EPSa*ste rel<=1e-8):
//     lte' = fma(ax, v, cl),              cl = fma(oma, lte, EPSa)
//     D'   = fma(omg, pre, K),            pre = fma(oma, D, ax), K = fma(EPSg, lte', gx)
//     u'   = rcp(D');  v' = lte'*u'       (v = rcp(ste) carried as product)
//   Critical cycle: D->rcp->v->lte'->K->D' = 1 rcp + 4 VALU (was 2 rcp + 2 fma).
//   Issue: 1 rcp + 8 VALU (was 2 rcp + 6 VALU).
//   Consumers reconstruct: ste = D*rcp(lte), y = x*rcp(D) (r17/r18-validated
//   y form; consumers have >=3x slack for the extra rcps).
// Structure (r18, 68.6us): 256 blocks x 32 rows; wave0 producer (lanes 0..31,
// full-tile x register prefetch, 1-tile lead covers barrier vmcnt drain);
// waves 1-2 consumers (stores + s/y reconstruction); 1 barrier/tile.
// Lessons: r6 parallel-in-time broken (s ~ 20*EPS); r9 producer loads need
// >= 1-tile lead; r4/r12/r17 never pack 2 chains into one wave.

constexpr int   T    = 2048;
constexpr int   B    = 8192;
constexpr int   RPB  = 32;        // rows per block
constexpr int   TT   = 64;        // steps per tile
constexpr int   NTI  = T / TT;    // 32 tiles
constexpr int   LSX  = 68;        // LDS stride words: 272B rows, 16B-aligned
constexpr float EPS  = 1e-8f;

__global__ __launch_bounds__(192, 1)
void hw_kernel(const float* __restrict__ x,
               const float* __restrict__ pla,
               const float* __restrict__ plg,
               float* __restrict__ out)
{
    __shared__ alignas(16) float LT[2][RPB][LSX];   // lte = l + EPS
    __shared__ alignas(16) float DT[2][RPB][LSX];   // D = lte * ste

    const int tid  = threadIdx.x;
    const int wid  = tid >> 6;        // 0 = producer, 1..2 = consumers
    const int lane = tid & 63;
    const int row0 = blockIdx.x * RPB;

    const float alpha = 1.0f / (1.0f + expf(-pla[0]));
    const float gamma = 1.0f / (1.0f + expf(-plg[0]));
    const float oma = 1.0f - alpha, omg = 1.0f - gamma;
    const float EPSa = EPS * alpha;
    const float EPSg = EPS * gamma;

    float* __restrict__ lout = out;
    float* __restrict__ sout = out + (size_t)B * T;
    float* __restrict__ yout = out + (size_t)2 * B * T;

    // store-phase lane mapping
    const int cr = lane >> 4;          // 0..3
    const int cc = (lane & 15) << 2;   // 0,4,...,60

    // consumer: l from LDS; s = D*rcp(l); y = x*rcp(D)
    auto store_tile = [&](int m, int itlo, int ithi) {
        const int bsel = m & 1;
        const int t0 = m * TT;
        for (int it = itlo; it < ithi; ++it) {
            const int r = 4 * it + cr;
            const size_t g = (size_t)(row0 + r) * T + t0 + cc;
            const float4 vl = *reinterpret_cast<const float4*>(&LT[bsel][r][cc]);
            const float4 vd = *reinterpret_cast<const float4*>(&DT[bsel][r][cc]);
            const float4 xv = *reinterpret_cast<const float4*>(&x[g]);
            float4 vs, vy;
            vs.x = vd.x * __builtin_amdgcn_rcpf(vl.x);
            vs.y = vd.y * __builtin_amdgcn_rcpf(vl.y);
            vs.z = vd.z * __builtin_amdgcn_rcpf(vl.z);
            vs.w = vd.w * __builtin_amdgcn_rcpf(vl.w);
            vy.x = xv.x * __builtin_amdgcn_rcpf(vd.x);
            vy.y = xv.y * __builtin_amdgcn_rcpf(vd.y);
            vy.z = xv.z * __builtin_amdgcn_rcpf(vd.z);
            vy.w = xv.w * __builtin_amdgcn_rcpf(vd.w);
            *reinterpret_cast<float4*>(&lout[g]) = vl;
            *reinterpret_cast<float4*>(&sout[g]) = vs;
            *reinterpret_cast<float4*>(&yout[g]) = vy;
        }
    };

    if (wid == 0) {
        // ================= producer =================
        const bool act = lane < RPB;
        const float* __restrict__ xrow = x + (size_t)(row0 + (act ? lane : 0)) * T;

        float lte = 0.0f;   // l + EPS
        float D   = 1.0f;   // lte * ste
        float v   = 1.0f;   // rcp(ste), carried as lte*rcp(D)
        float4 XA[16], XB[16];

        auto loadX = [&](float4* Xb, int k) {
            const float* p = xrow + k * TT;
            #pragma unroll
            for (int i = 0; i < 16; ++i)
                Xb[i] = *reinterpret_cast<const float4*>(p + 4 * i);
        };

        // ONE-rcp step: cycle D -> u(rcp) -> v(mul) -> lte'(fma) -> K(fma) -> D'(fma)
        auto do_step = [&](float xt, float& lo, float& dsto) {
            const float ax  = alpha * xt;                       // off-chain
            const float gx  = gamma * xt;                       // off-chain
            const float cl  = __builtin_fmaf(oma, lte, EPSa);   // off-chain
            const float pre = __builtin_fmaf(oma, D, ax);       // off-chain
            const float ltn = __builtin_fmaf(ax, v, cl);        // chain (= l'+EPS)
            const float K   = __builtin_fmaf(EPSg, ltn, gx);    // chain
            const float Dn  = __builtin_fmaf(omg, pre, K);      // chain (= lte'*ste')
            const float un  = __builtin_amdgcn_rcpf(Dn);        // chain (the one rcp)
            const float vn  = ltn * un;                         // chain (= rcp(ste'))
            lo = ltn; dsto = Dn;
            lte = ltn; D = Dn; v = vn;
        };

        auto compute_tile = [&](const float4* Xb, int k, bool first) {
            const int bsel = k & 1;
            #pragma unroll
            for (int g = 0; g < 16; ++g) {
                const float4 xv = Xb[g];
                float4 lv, dv;
                if (first && g == 0) {
                    // t == 0: l0 = x0, s0 = 1 (primed): lte = x0+e, ste = 1+e
                    lte = xv.x + EPS;
                    const float ste0 = 1.0f + EPS;
                    D = lte * ste0;
                    v = lte * __builtin_amdgcn_rcpf(D);
                    lv.x = lte; dv.x = D;
                    do_step(xv.y, lv.y, dv.y);
                    do_step(xv.z, lv.z, dv.z);
                    do_step(xv.w, lv.w, dv.w);
                } else {
                    do_step(xv.x, lv.x, dv.x);
                    do_step(xv.y, lv.y, dv.y);
                    do_step(xv.z, lv.z, dv.z);
                    do_step(xv.w, lv.w, dv.w);
                }
                *reinterpret_cast<float4*>(&LT[bsel][lane][4 * g]) = lv;
                *reinterpret_cast<float4*>(&DT[bsel][lane][4 * g]) = dv;
            }
        };

        if (act) { loadX(XA, 0); loadX(XB, 1); }
        if (act) compute_tile(XA, 0, true);     // one-time vmcnt wait on XA
        __syncthreads();

        #pragma unroll 1
        for (int k = 1; k < NTI - 1; k += 2) {
            if (act) { loadX(XA, k + 1); compute_tile(XB, k, false); }
            __syncthreads();
            if (act) { loadX(XB, k + 2); compute_tile(XA, k + 1, false); }
            __syncthreads();
        }
        if (act) compute_tile(XB, NTI - 1, false);
        __syncthreads();
    } else {
        // ================= consumers: stores + s/y reconstruction =========
        const int lo = (wid - 1) * 4;            // wave1: 0..3, wave2: 4..7
        #pragma unroll 1
        for (int k = 0; k < NTI; ++k) {
            if (k > 0) store_tile(k - 1, lo, lo + 4);
            __syncthreads();
        }
    }

    // epilogue: tile 31 (buffer 1), all three waves split the 8 store groups
    {
        const int lo = (wid == 0) ? 0 : (wid == 1) ? 2 : 5;
        const int hi = (wid == 0) ? 2 : (wid == 1) ? 5 : 8;
        store_tile(NTI - 1, lo, hi);
    }
}

extern "C" void kernel_launch(void* const* d_in, const int* in_sizes, int n_in,
                              void* d_out, int out_size, void* d_ws, size_t ws_size,
                              hipStream_t stream) {
    const float* x   = (const float*)d_in[0];
    const float* pla = (const float*)d_in[1];
    const float* plg = (const float*)d_in[2];
    float* out = (float*)d_out;

    dim3 grid(B / RPB);    // 256 blocks -> one producer + 2 consumers per CU
    dim3 block(192);       // wave0 producer (32 rows), waves 1-2 consumers
    hw_kernel<<<grid, block, 0, stream>>>(x, pla, plg, out);
}